// Round 1
// baseline (4065.298 us; speedup 1.0000x reference)
//
#include <hip/hip_runtime.h>

typedef _Float16 f16;
typedef _Float16 f16x8 __attribute__((ext_vector_type(8)));
typedef float    f32x4 __attribute__((ext_vector_type(4)));

#define MFMA16(a, b, c) __builtin_amdgcn_mfma_f32_16x16x32_f16((a), (b), (c), 0, 0, 0)

// Sizes
// DIM=128, HID=512, N=512, IN=257, MLP_H=2048, NC=128
// h element counts
#define HSZ 262144            // 512*512
#define LOGDET_C 235.2482644923962f  // 128*log(2*pi)

// ---------------------------------------------------------------------------
// prep: base = [x*mask, mask] @ Wih0[:,1:257]^T + b_ih0 + b_hh0  (f32)
//       convert recurrent/MLP weights to f16; zero h0[0], h1_all[0]
// grid 256 x 256
__global__ void k_prep(const float* __restrict__ x, const float* __restrict__ mask,
                       const float* __restrict__ Wih0,
                       const float* __restrict__ b_ih0, const float* __restrict__ b_hh0,
                       const float* __restrict__ Whh0, const float* __restrict__ Wih1,
                       const float* __restrict__ Whh1, const float* __restrict__ W1,
                       const float* __restrict__ W2,
                       float* __restrict__ base, f16* __restrict__ Whh0h,
                       f16* __restrict__ Wih1h, f16* __restrict__ Whh1h,
                       f16* __restrict__ W1h, f16* __restrict__ W2h,
                       f16* __restrict__ h0buf, f16* __restrict__ h1all)
{
    int gid = blockIdx.x * 256 + threadIdx.x;   // 0..65535
    // base: 262144 outputs, 4 per thread
    for (int i = 0; i < 4; i++) {
        int idx = gid + 65536 * i;
        int r = idx >> 9, c = idx & 511;
        const float* wrow = Wih0 + c * 257;
        float s = b_ih0[c] + b_hh0[c];
        for (int k = 0; k < 128; k++) s += x[r * 128 + k] * mask[k] * wrow[1 + k];
        for (int k = 0; k < 128; k++) s += mask[k] * wrow[129 + k];
        base[idx] = s;
    }
    // weight conversions
    for (int i = gid; i < 262144; i += 65536) {
        Whh0h[i] = (f16)Whh0[i];
        Wih1h[i] = (f16)Wih1[i];
        Whh1h[i] = (f16)Whh1[i];
    }
    for (int i = gid; i < 1048576; i += 65536) W1h[i] = (f16)W1[i];
    for (int i = gid; i < 524288;  i += 65536) W2h[i] = (f16)W2[i];
    // zero initial states
    for (int i = gid; i < HSZ; i += 65536) {
        h0buf[i] = (f16)0.f;
        h1all[i] = (f16)0.f;
    }
}

// ---------------------------------------------------------------------------
// S1: h0out = tanh(base + prev*Wih0[:,0] + h0in @ Whh0^T)
// grid 256 wgs: tile 32x32, 4 waves K-split (128 each), LDS reduce.
__global__ __launch_bounds__(256) void k_s1(const f16* __restrict__ h0in,
                                            f16* __restrict__ h0out,
                                            const float* __restrict__ base,
                                            const float* __restrict__ x,
                                            const float* __restrict__ Wih0,
                                            const f16* __restrict__ Whh0h, int step)
{
    __shared__ float part[4][32][32];
    int tid = threadIdx.x;
    int w = tid >> 6, l = tid & 63;
    int R0 = (blockIdx.x >> 4) * 32, C0 = (blockIdx.x & 15) * 32;
    int lr = l & 15, hi = l >> 4, lk = hi * 8;

    f32x4 acc00 = {0.f, 0.f, 0.f, 0.f}, acc01 = acc00, acc10 = acc00, acc11 = acc00;
    const f16* a0p = h0in  + (R0 + lr) * 512 + w * 128 + lk;
    const f16* b0p = Whh0h + (C0 + lr) * 512 + w * 128 + lk;
#pragma unroll
    for (int km = 0; km < 4; km++) {
        f16x8 a0 = *(const f16x8*)(a0p + km * 32);
        f16x8 a1 = *(const f16x8*)(a0p + km * 32 + 16 * 512);
        f16x8 b0 = *(const f16x8*)(b0p + km * 32);
        f16x8 b1 = *(const f16x8*)(b0p + km * 32 + 16 * 512);
        acc00 = MFMA16(a0, b0, acc00);
        acc01 = MFMA16(a0, b1, acc01);
        acc10 = MFMA16(a1, b0, acc10);
        acc11 = MFMA16(a1, b1, acc11);
    }
#pragma unroll
    for (int r = 0; r < 4; r++) {
        part[w][hi * 4 + r][lr]           = acc00[r];
        part[w][hi * 4 + r][16 + lr]      = acc01[r];
        part[w][16 + hi * 4 + r][lr]      = acc10[r];
        part[w][16 + hi * 4 + r][16 + lr] = acc11[r];
    }
    __syncthreads();
    int rr = tid >> 3, c0 = (tid & 7) * 4;
    int gr = R0 + rr;
    float prevv = (step > 0) ? x[gr * 128 + step - 1] : 0.f;
#pragma unroll
    for (int cc = 0; cc < 4; cc++) {
        int gc = C0 + c0 + cc;
        float s = part[0][rr][c0 + cc] + part[1][rr][c0 + cc] +
                  part[2][rr][c0 + cc] + part[3][rr][c0 + cc];
        s += base[gr * 512 + gc] + prevv * Wih0[gc * 257];
        h0out[gr * 512 + gc] = (f16)tanhf(s);
    }
}

// ---------------------------------------------------------------------------
// S2: h1out = tanh(h0now @ Wih1^T + h1in @ Whh1^T + b_ih1 + b_hh1)
__global__ __launch_bounds__(256) void k_s2(const f16* __restrict__ h0now,
                                            const f16* __restrict__ h1in,
                                            f16* __restrict__ h1out,
                                            const f16* __restrict__ Wih1h,
                                            const f16* __restrict__ Whh1h,
                                            const float* __restrict__ b_ih1,
                                            const float* __restrict__ b_hh1)
{
    __shared__ float part[4][32][32];
    int tid = threadIdx.x;
    int w = tid >> 6, l = tid & 63;
    int R0 = (blockIdx.x >> 4) * 32, C0 = (blockIdx.x & 15) * 32;
    int lr = l & 15, hi = l >> 4, lk = hi * 8;

    f32x4 acc00 = {0.f, 0.f, 0.f, 0.f}, acc01 = acc00, acc10 = acc00, acc11 = acc00;
    {
        const f16* a0p = h0now + (R0 + lr) * 512 + w * 128 + lk;
        const f16* b0p = Wih1h + (C0 + lr) * 512 + w * 128 + lk;
#pragma unroll
        for (int km = 0; km < 4; km++) {
            f16x8 a0 = *(const f16x8*)(a0p + km * 32);
            f16x8 a1 = *(const f16x8*)(a0p + km * 32 + 16 * 512);
            f16x8 b0 = *(const f16x8*)(b0p + km * 32);
            f16x8 b1 = *(const f16x8*)(b0p + km * 32 + 16 * 512);
            acc00 = MFMA16(a0, b0, acc00);
            acc01 = MFMA16(a0, b1, acc01);
            acc10 = MFMA16(a1, b0, acc10);
            acc11 = MFMA16(a1, b1, acc11);
        }
    }
    {
        const f16* a0p = h1in  + (R0 + lr) * 512 + w * 128 + lk;
        const f16* b0p = Whh1h + (C0 + lr) * 512 + w * 128 + lk;
#pragma unroll
        for (int km = 0; km < 4; km++) {
            f16x8 a0 = *(const f16x8*)(a0p + km * 32);
            f16x8 a1 = *(const f16x8*)(a0p + km * 32 + 16 * 512);
            f16x8 b0 = *(const f16x8*)(b0p + km * 32);
            f16x8 b1 = *(const f16x8*)(b0p + km * 32 + 16 * 512);
            acc00 = MFMA16(a0, b0, acc00);
            acc01 = MFMA16(a0, b1, acc01);
            acc10 = MFMA16(a1, b0, acc10);
            acc11 = MFMA16(a1, b1, acc11);
        }
    }
#pragma unroll
    for (int r = 0; r < 4; r++) {
        part[w][hi * 4 + r][lr]           = acc00[r];
        part[w][hi * 4 + r][16 + lr]      = acc01[r];
        part[w][16 + hi * 4 + r][lr]      = acc10[r];
        part[w][16 + hi * 4 + r][16 + lr] = acc11[r];
    }
    __syncthreads();
    int rr = tid >> 3, c0 = (tid & 7) * 4;
    int gr = R0 + rr;
#pragma unroll
    for (int cc = 0; cc < 4; cc++) {
        int gc = C0 + c0 + cc;
        float s = part[0][rr][c0 + cc] + part[1][rr][c0 + cc] +
                  part[2][rr][c0 + cc] + part[3][rr][c0 + cc];
        s += b_ih1[gc] + b_hh1[gc];
        h1out[gr * 512 + gc] = (f16)tanhf(s);
    }
}

// ---------------------------------------------------------------------------
// Phase B (fully parallel over (t, row-tile)):
//   hid = relu(h1_all[t+1] @ W1^T + b1); mc = hid @ W2^T + b2
//   pcontrib[t][row] = -0.5*(C + quad) - 0.5*sum(log(softplus(cov)))
// grid 1024 wgs (t = bid&127, rtile = bid>>7); wave = 16 rows x all 256 mc cols.
__global__ __launch_bounds__(256) void k_phaseB(const f16* __restrict__ h1all,
                                                const f16* __restrict__ W1h,
                                                const f16* __restrict__ W2h,
                                                const float* __restrict__ b1,
                                                const float* __restrict__ b2,
                                                const float* __restrict__ x,
                                                float* __restrict__ pcontrib)
{
    __shared__ __align__(16) f16 hidlds[4][16][72];
    int tid = threadIdx.x;
    int w = tid >> 6, l = tid & 63;
    int t = blockIdx.x & 127, rtile = blockIdx.x >> 7;
    int R0 = rtile * 64 + w * 16;
    int lr = l & 15, hi = l >> 4, lk = hi * 8;
    const f16* H = h1all + (size_t)(t + 1) * HSZ;

    f32x4 mc[16] = {};
    for (int nc = 0; nc < 2048; nc += 64) {
        // S3: hid chunk [16 rows][64 cols]
        f32x4 acc3[4] = {};
        for (int kc = 0; kc < 16; kc++) {
            f16x8 a = *(const f16x8*)(H + (R0 + lr) * 512 + kc * 32 + lk);
#pragma unroll
            for (int ns = 0; ns < 4; ns++) {
                f16x8 b = *(const f16x8*)(W1h + (size_t)(nc + ns * 16 + lr) * 512 + kc * 32 + lk);
                acc3[ns] = MFMA16(a, b, acc3[ns]);
            }
        }
        // bias + relu -> LDS (wave-private)
#pragma unroll
        for (int ns = 0; ns < 4; ns++) {
#pragma unroll
            for (int r = 0; r < 4; r++) {
                float v = acc3[ns][r] + b1[nc + ns * 16 + lr];
                hidlds[w][hi * 4 + r][ns * 16 + lr] = (f16)fmaxf(v, 0.f);
            }
        }
        // S4: mc[16][256] += hid_chunk @ W2[:, nc:nc+64]^T
#pragma unroll
        for (int k4 = 0; k4 < 2; k4++) {
            f16x8 a4 = *(const f16x8*)(&hidlds[w][lr][k4 * 32 + lk]);
#pragma unroll
            for (int ms = 0; ms < 16; ms++) {
                f16x8 b = *(const f16x8*)(W2h + (size_t)(ms * 16 + lr) * 2048 + nc + k4 * 32 + lk);
                mc[ms] = MFMA16(a4, b, mc[ms]);
            }
        }
    }
    // epilogue: per-lane it holds mean (cols c) and cov (cols c+128) for the SAME (row,c)
    float quad[4] = {0.f, 0.f, 0.f, 0.f};
    float lsum[4] = {0.f, 0.f, 0.f, 0.f};
    float xt[4];
#pragma unroll
    for (int r = 0; r < 4; r++) xt[r] = x[(R0 + hi * 4 + r) * 128 + t];
#pragma unroll
    for (int ns = 0; ns < 8; ns++) {
        int c = ns * 16 + lr;
        float bm = b2[c], bc = b2[128 + c];
#pragma unroll
        for (int r = 0; r < 4; r++) {
            float mean = mc[ns][r] + bm;
            float cov  = mc[ns + 8][r] + bc;
            float sp = log1pf(expf(-fabsf(cov))) + fmaxf(cov, 0.f);  // softplus
            float d = xt[r] - mean;
            quad[r] += d * d * sp;
            lsum[r] += logf(sp);
        }
    }
#pragma unroll
    for (int m = 1; m < 16; m <<= 1) {
#pragma unroll
        for (int r = 0; r < 4; r++) {
            quad[r] += __shfl_xor(quad[r], m, 64);
            lsum[r] += __shfl_xor(lsum[r], m, 64);
        }
    }
    if (lr == 0) {
#pragma unroll
        for (int r = 0; r < 4; r++) {
            pcontrib[t * 512 + R0 + hi * 4 + r] =
                -0.5f * (LOGDET_C + quad[r]) - 0.5f * lsum[r];
        }
    }
}

// ---------------------------------------------------------------------------
// finalize: out[0:262144] = (float)h1_all[128]; out[262144+r] = sum_t pcontrib
__global__ void k_fin(const f16* __restrict__ h1last,
                      const float* __restrict__ pcontrib, float* __restrict__ out)
{
    int gid = blockIdx.x * 256 + threadIdx.x;   // 512 wgs -> 131072 threads
    for (int i = gid; i < HSZ; i += 131072) out[i] = (float)h1last[i];
    if (gid < 512) {
        float s = 0.f;
        for (int tt = 0; tt < 128; tt++) s += pcontrib[tt * 512 + gid];
        out[HSZ + gid] = s;
    }
}

// ---------------------------------------------------------------------------
extern "C" void kernel_launch(void* const* d_in, const int* in_sizes, int n_in,
                              void* d_out, int out_size, void* d_ws, size_t ws_size,
                              hipStream_t stream) {
    const float* x     = (const float*)d_in[0];
    const float* mask  = (const float*)d_in[1];
    const float* Wih0  = (const float*)d_in[2];
    const float* Whh0  = (const float*)d_in[3];
    const float* b_ih0 = (const float*)d_in[4];
    const float* b_hh0 = (const float*)d_in[5];
    const float* Wih1  = (const float*)d_in[6];
    const float* Whh1  = (const float*)d_in[7];
    const float* b_ih1 = (const float*)d_in[8];
    const float* b_hh1 = (const float*)d_in[9];
    const float* W1    = (const float*)d_in[10];
    const float* b1    = (const float*)d_in[11];
    const float* W2    = (const float*)d_in[12];
    const float* b2    = (const float*)d_in[13];

    char* ws = (char*)d_ws;
    size_t off = 0;
    auto take = [&](size_t bytes) { char* p = ws + off; off += (bytes + 255) & ~(size_t)255; return p; };
    float* base    = (float*)take(512 * 512 * 4);
    f16* Whh0h     = (f16*)take(HSZ * 2);
    f16* Wih1h     = (f16*)take(HSZ * 2);
    f16* Whh1h     = (f16*)take(HSZ * 2);
    f16* W1h       = (f16*)take(1048576 * 2);
    f16* W2h       = (f16*)take(524288 * 2);
    f16* h0buf     = (f16*)take(2 * HSZ * 2);
    f16* h1all     = (f16*)take((size_t)129 * HSZ * 2);
    float* pcontrib= (float*)take(128 * 512 * 4);
    if (off > ws_size) return;   // workspace too small: fail cleanly

    k_prep<<<256, 256, 0, stream>>>(x, mask, Wih0, b_ih0, b_hh0, Whh0, Wih1, Whh1,
                                    W1, W2, base, Whh0h, Wih1h, Whh1h, W1h, W2h,
                                    h0buf, h1all);
    for (int s = 0; s < 128; s++) {
        f16* h0_rd = h0buf + (s & 1) * HSZ;
        f16* h0_wr = h0buf + ((s & 1) ^ 1) * HSZ;
        k_s1<<<256, 256, 0, stream>>>(h0_rd, h0_wr, base, x, Wih0, Whh0h, s);
        k_s2<<<256, 256, 0, stream>>>(h0_wr, h1all + (size_t)s * HSZ,
                                      h1all + (size_t)(s + 1) * HSZ,
                                      Wih1h, Whh1h, b_ih1, b_hh1);
    }
    k_phaseB<<<1024, 256, 0, stream>>>(h1all, W1h, W2h, b1, b2, x, pcontrib);
    k_fin<<<512, 256, 0, stream>>>(h1all + (size_t)128 * HSZ, pcontrib, (float*)d_out);
}